// Round 4
// baseline (1366.508 us; speedup 1.0000x reference)
//
#include <hip/hip_runtime.h>
#include <hip/hip_cooperative_groups.h>
#include <math.h>

namespace cg = cooperative_groups;

#define EPS 1e-6f
#define NE 64
#define NBLK 256
#define TPB 1024
#define WPB 16          // waves per block
#define ITERS 10
#define MAXROWS 2048    // rows per block (S=524288 / 256)

// ---- DPP helpers: 16-lane-group reductions, pure VALU ----
template <int ctrl>
__device__ __forceinline__ float dppf(float x) {
    return __int_as_float(__builtin_amdgcn_update_dpp(
        0, __float_as_int(x), ctrl, 0xf, 0xf, true));
}
template <int ctrl>
__device__ __forceinline__ int dppi(int x) {
    return __builtin_amdgcn_update_dpp(0, x, ctrl, 0xf, 0xf, true);
}

__device__ __forceinline__ float group16_sum(float v) {
    v += dppf<0xB1>(v);   // quad_perm xor 1
    v += dppf<0x4E>(v);   // quad_perm xor 2
    v += dppf<0x141>(v);  // row_half_mirror (xor 4)
    v += dppf<0x140>(v);  // row_mirror (xor 8)
    return v;
}

#define ARGMAX_STEP(CTRL)                                      \
    {                                                          \
        float ov = dppf<CTRL>(v);                              \
        int oi = dppi<CTRL>(i);                                \
        if (ov > v || (ov == v && oi < i)) { v = ov; i = oi; } \
    }

__device__ __forceinline__ void group16_argmax(float& v, int& i) {
    ARGMAX_STEP(0xB1)
    ARGMAX_STEP(0x4E)
    ARGMAX_STEP(0x141)
    ARGMAX_STEP(0x140)
}

// Single persistent kernel: 10 Sinkhorn iterations + final top-2.
// ws: Pblk = 2 * NBLK * NE floats (ping-pong block partials).
__global__ __launch_bounds__(TPB, 1) void sink_all(
    const float4* __restrict__ logits4, float* __restrict__ Pblk,
    float2* __restrict__ oidx, float2* __restrict__ ow, int nquads,
    float col_target) {
    cg::grid_group grid = cg::this_grid();
    const int tid = threadIdx.x;
    const int lane = tid & 63;
    const int wib = tid >> 6;
    const int g = lane >> 4;       // row within quad
    const int h = lane & 15;       // float4 slot within row
    const int qpw = nquads / (NBLK * WPB);          // quads per wave (32)
    const int qbase = (blockIdx.x * WPB + wib) * qpw;

    __shared__ float s_r[MAXROWS];          // per-block row scalings
    __shared__ float s_c[NE];               // column scaling (identical all blocks)
    __shared__ float4 s_pl[WPB][64];        // wave partial staging / reduce buf
    float* s_red = (float*)s_pl;            // aliased [16][64] reduce buffer

    for (int i = tid; i < MAXROWS; i += TPB) s_r[i] = 1.0f;
    if (tid < NE) s_c[tid] = 1.0f;
    __syncthreads();

    for (int it = 0; it < ITERS; ++it) {
        // --- row phase: update r (LDS), accumulate column partials ---
        float4 c4;
        c4.x = s_c[h * 4 + 0]; c4.y = s_c[h * 4 + 1];
        c4.z = s_c[h * 4 + 2]; c4.w = s_c[h * 4 + 3];

        float4 pacc = {0.f, 0.f, 0.f, 0.f};
        float4 v = logits4[(size_t)qbase * 64 + lane];
        for (int k = 0; k < qpw; ++k) {
            float4 cur = v;
            if (k + 1 < qpw)
                v = logits4[(size_t)(qbase + k + 1) * 64 + lane];  // prefetch
            float4 q;
            q.x = __expf(cur.x); q.y = __expf(cur.y);
            q.z = __expf(cur.z); q.w = __expf(cur.w);
            float s = q.x * c4.x + q.y * c4.y + q.z * c4.z + q.w * c4.w;
            s = group16_sum(s);
            int lrow = (wib * qpw + k) * 4 + g;
            float rold = s_r[lrow];
            float rnew = rold / (rold * s + EPS);
            if (h == 0) s_r[lrow] = rnew;
            pacc.x += q.x * rnew; pacc.y += q.y * rnew;
            pacc.z += q.z * rnew; pacc.w += q.w * rnew;
        }

        // --- block-level column reduction (fixed order), write partials ---
        __syncthreads();           // protect s_pl reuse from previous phase
        s_pl[wib][lane] = pacc;
        __syncthreads();
        float* Pout = Pblk + (size_t)(it & 1) * NBLK * NE;
        if (tid < NE) {
            int j = tid, hh = j >> 2, kk = j & 3;
            float t = 0.f;
#pragma unroll
            for (int w = 0; w < WPB; ++w)
#pragma unroll
                for (int gg = 0; gg < 4; ++gg)
                    t += ((const float*)&s_pl[w][gg * 16 + hh])[kk];
            Pout[blockIdx.x * NE + j] = t;
        }
        __threadfence();
        grid.sync();

        // --- redundant deterministic c update (identical in every block) ---
        const float* Pin = Pblk + (size_t)(it & 1) * NBLK * NE;
        {
            int j = tid & 63;
            int chunk = tid >> 6;                 // 16 chunks of 16 blocks
            float t = 0.f;
            int b0 = chunk * (NBLK / 16);
            for (int b = b0; b < b0 + NBLK / 16; ++b) t += Pin[b * NE + j];
            __syncthreads();                      // s_pl free for reuse
            s_red[chunk * NE + j] = t;
            __syncthreads();
            if (tid < NE) {
                float P = 0.f;
#pragma unroll
                for (int k = 0; k < 16; ++k) P += s_red[k * NE + tid];
                float cj = s_c[tid];
                s_c[tid] = cj * col_target / (cj * P + EPS);
            }
            __syncthreads();
        }
    }

    // --- final: row-normalize with final c, top-2, renormalize ---
    float4 c4;
    c4.x = s_c[h * 4 + 0]; c4.y = s_c[h * 4 + 1];
    c4.z = s_c[h * 4 + 2]; c4.w = s_c[h * 4 + 3];
    const int base_col = h * 4;

    float4 v = logits4[(size_t)qbase * 64 + lane];
    for (int k = 0; k < qpw; ++k) {
        float4 cur = v;
        if (k + 1 < qpw)
            v = logits4[(size_t)(qbase + k + 1) * 64 + lane];
        float4 u;
        u.x = __expf(cur.x) * c4.x; u.y = __expf(cur.y) * c4.y;
        u.z = __expf(cur.z) * c4.z; u.w = __expf(cur.w) * c4.w;
        float s = group16_sum(u.x + u.y + u.z + u.w);
        int lrow = (wib * qpw + k) * 4 + g;
        float rold = s_r[lrow];
        float rnew = rold / (rold * s + EPS);
        float4 val;
        val.x = u.x * rnew; val.y = u.y * rnew;
        val.z = u.z * rnew; val.w = u.w * rnew;

        float vv = val.x; int i = base_col;
        if (val.y > vv) { vv = val.y; i = base_col + 1; }
        if (val.z > vv) { vv = val.z; i = base_col + 2; }
        if (val.w > vv) { vv = val.w; i = base_col + 3; }
        { float& v = vv; group16_argmax(v, i); }
        float v1 = vv; int i1 = i;

        float4 mv;
        mv.x = (i1 == base_col)     ? -INFINITY : val.x;
        mv.y = (i1 == base_col + 1) ? -INFINITY : val.y;
        mv.z = (i1 == base_col + 2) ? -INFINITY : val.z;
        mv.w = (i1 == base_col + 3) ? -INFINITY : val.w;
        vv = mv.x; i = base_col;
        if (mv.y > vv) { vv = mv.y; i = base_col + 1; }
        if (mv.z > vv) { vv = mv.z; i = base_col + 2; }
        if (mv.w > vv) { vv = mv.w; i = base_col + 3; }
        { float& v = vv; group16_argmax(v, i); }
        float v2 = vv; int i2 = i;

        if (h == 0) {
            int row = (qbase + k) * 4 + g;
            float wsum = v1 + v2 + EPS;
            oidx[row] = make_float2((float)i1, (float)i2);
            ow[row] = make_float2(v1 / wsum, v2 / wsum);
        }
    }
}

extern "C" void kernel_launch(void* const* d_in, const int* in_sizes, int n_in,
                              void* d_out, int out_size, void* d_ws, size_t ws_size,
                              hipStream_t stream) {
    const float* logits = (const float*)d_in[0];
    const int S = in_sizes[0] / NE;            // 524288
    int nquads = S / 4;
    float col_target = (float)S / (float)NE;

    float* Pblk = (float*)d_ws;                // 2*NBLK*NE floats

    float* out = (float*)d_out;
    float2* oidx = (float2*)out;               // 2*S floats (indices)
    float2* ow = (float2*)(out + (size_t)2 * S);  // 2*S floats (weights)

    const float4* logits4 = (const float4*)logits;
    void* args[] = {(void*)&logits4, (void*)&Pblk, (void*)&oidx,
                    (void*)&ow, (void*)&nquads, (void*)&col_target};
    hipLaunchCooperativeKernel((void*)sink_all, dim3(NBLK), dim3(TPB), args,
                               0, stream);
}

// Round 5
// 614.001 us; speedup vs baseline: 2.2256x; 2.2256x over previous
//
#include <hip/hip_runtime.h>
#include <math.h>

#define EPS 1e-6f
#define NE 64
#define THREADS 256
#define WPB 4              // waves per block
#define NBLOCKS 1024
#define NWAVES (NBLOCKS * WPB)   // 4096
#define ITERS 10
#define PF 4               // prefetch depth (quads per batch)

// ---- DPP helpers: 16-lane-group reductions, pure VALU (no ds ops) ----
template <int ctrl>
__device__ __forceinline__ float dppf(float x) {
    return __int_as_float(__builtin_amdgcn_update_dpp(
        0, __float_as_int(x), ctrl, 0xf, 0xf, true));
}
template <int ctrl>
__device__ __forceinline__ int dppi(int x) {
    return __builtin_amdgcn_update_dpp(0, x, ctrl, 0xf, 0xf, true);
}

__device__ __forceinline__ float group16_sum(float v) {
    v += dppf<0xB1>(v);   // quad_perm xor 1
    v += dppf<0x4E>(v);   // quad_perm xor 2
    v += dppf<0x141>(v);  // row_half_mirror (xor 4)
    v += dppf<0x140>(v);  // row_mirror (xor 8)
    return v;
}

#define ARGMAX_STEP(CTRL)                                      \
    {                                                          \
        float ov = dppf<CTRL>(v);                              \
        int oi = dppi<CTRL>(i);                                \
        if (ov > v || (ov == v && oi < i)) { v = ov; i = oi; } \
    }

__device__ __forceinline__ void group16_argmax(float& v, int& i) {
    ARGMAX_STEP(0xB1)
    ARGMAX_STEP(0x4E)
    ARGMAX_STEP(0x141)
    ARGMAX_STEP(0x140)
}

// ws layout: r[S] | c[64] | Pblk[NBLOCKS*64]
// Static slices: wave (blk*WPB+wib) owns quads [w*qpw, (w+1)*qpw).
// One Sinkhorn iteration: update r, write per-block column partials (no
// atomics -> deterministic). FIRST folds r=c=1 init (no init kernel).
template <bool FIRST>
__global__ __launch_bounds__(THREADS) void sink_pass(
    const float4* __restrict__ logits4, float* __restrict__ r,
    const float* __restrict__ c, float* __restrict__ Pblk, int nquads) {
    const int lane = threadIdx.x & 63;
    const int wib = threadIdx.x >> 6;
    const int g = lane >> 4;   // row within quad
    const int h = lane & 15;   // float4 slot within row
    const int qpw = nquads / NWAVES;                 // 32
    const int qbase = (blockIdx.x * WPB + wib) * qpw;

    float4 c4;
    if (FIRST) c4 = make_float4(1.f, 1.f, 1.f, 1.f);
    else       c4 = ((const float4*)c)[h];

    const float4* lp = logits4 + (size_t)qbase * 64 + lane;

    float4 buf[PF];
    float rbuf[PF];
#pragma unroll
    for (int p = 0; p < PF; ++p) buf[p] = lp[(size_t)p * 64];
    if (!FIRST) {
#pragma unroll
        for (int p = 0; p < PF; ++p) rbuf[p] = r[(qbase + p) * 4 + g];
    }

    float4 pacc = {0.f, 0.f, 0.f, 0.f};
    const int nb = qpw / PF;
    for (int b = 0; b < nb; ++b) {
        float4 cur[PF];
        float rcur[PF];
#pragma unroll
        for (int p = 0; p < PF; ++p) {
            cur[p] = buf[p];
            if (!FIRST) rcur[p] = rbuf[p];
        }
        if (b + 1 < nb) {
            const float4* np = lp + (size_t)(b + 1) * PF * 64;
#pragma unroll
            for (int p = 0; p < PF; ++p) buf[p] = np[(size_t)p * 64];
            if (!FIRST) {
#pragma unroll
                for (int p = 0; p < PF; ++p)
                    rbuf[p] = r[(qbase + (b + 1) * PF + p) * 4 + g];
            }
        }
#pragma unroll
        for (int p = 0; p < PF; ++p) {
            float4 q;
            q.x = __expf(cur[p].x); q.y = __expf(cur[p].y);
            q.z = __expf(cur[p].z); q.w = __expf(cur[p].w);
            float s = q.x * c4.x + q.y * c4.y + q.z * c4.z + q.w * c4.w;
            s = group16_sum(s);
            float rold = FIRST ? 1.0f : rcur[p];
            float rnew = rold / (rold * s + EPS);
            int row = (qbase + b * PF + p) * 4 + g;
            if (h == 0) r[row] = rnew;
            pacc.x += q.x * rnew; pacc.y += q.y * rnew;
            pacc.z += q.z * rnew; pacc.w += q.w * rnew;
        }
    }

    // block-level column reduction (fixed order), plain store of partials
    __shared__ float4 plds[WPB][64];
    plds[wib][lane] = pacc;
    __syncthreads();
    if (threadIdx.x < NE) {
        int j = threadIdx.x;
        int hh = j >> 2, kk = j & 3;
        float t = 0.f;
#pragma unroll
        for (int w = 0; w < WPB; ++w)
#pragma unroll
            for (int gg = 0; gg < 4; ++gg)
                t += ((const float*)&plds[w][gg * 16 + hh])[kk];
        Pblk[blockIdx.x * NE + j] = t;
    }
}

// Deterministic column-sum over NBLOCKS partials (fixed order), then
// c_j <- c_j * T / (c_j * P_j + eps).  FIRST: c_prev = 1.
template <bool FIRST>
__global__ __launch_bounds__(1024) void sink_reduce(
    const float* __restrict__ Pblk, float* __restrict__ c, float col_target) {
    const int j = threadIdx.x & 63;
    const int chunk = threadIdx.x >> 6;   // 16 chunks of NBLOCKS/16 blocks
    const int per = NBLOCKS / 16;
    float t = 0.f;
    int b0 = chunk * per;
    for (int b = b0; b < b0 + per; ++b) t += Pblk[b * NE + j];
    __shared__ float lds[16][NE];
    lds[chunk][j] = t;
    __syncthreads();
    if (threadIdx.x < NE) {
        float P = 0.f;
#pragma unroll
        for (int k = 0; k < 16; ++k) P += lds[k][threadIdx.x];
        float cj = FIRST ? 1.0f : c[threadIdx.x];
        c[threadIdx.x] = cj * col_target / (cj * P + EPS);
    }
}

// Final: row-normalize + top-2 (DPP argmax, lowest-index ties) + renorm.
__global__ __launch_bounds__(THREADS) void sink_final(
    const float4* __restrict__ logits4, const float* __restrict__ r,
    const float* __restrict__ c, float2* __restrict__ oidx,
    float2* __restrict__ ow, int nquads) {
    const int lane = threadIdx.x & 63;
    const int wib = threadIdx.x >> 6;
    const int g = lane >> 4;
    const int h = lane & 15;
    const int base_col = h * 4;
    const int qpw = nquads / NWAVES;
    const int qbase = (blockIdx.x * WPB + wib) * qpw;

    const float4 c4 = ((const float4*)c)[h];
    const float4* lp = logits4 + (size_t)qbase * 64 + lane;

    float4 buf[PF];
    float rbuf[PF];
#pragma unroll
    for (int p = 0; p < PF; ++p) buf[p] = lp[(size_t)p * 64];
#pragma unroll
    for (int p = 0; p < PF; ++p) rbuf[p] = r[(qbase + p) * 4 + g];

    const int nb = qpw / PF;
    for (int b = 0; b < nb; ++b) {
        float4 cur[PF];
        float rcur[PF];
#pragma unroll
        for (int p = 0; p < PF; ++p) { cur[p] = buf[p]; rcur[p] = rbuf[p]; }
        if (b + 1 < nb) {
            const float4* np = lp + (size_t)(b + 1) * PF * 64;
#pragma unroll
            for (int p = 0; p < PF; ++p) buf[p] = np[(size_t)p * 64];
#pragma unroll
            for (int p = 0; p < PF; ++p)
                rbuf[p] = r[(qbase + (b + 1) * PF + p) * 4 + g];
        }
#pragma unroll
        for (int p = 0; p < PF; ++p) {
            float4 u;
            u.x = __expf(cur[p].x) * c4.x; u.y = __expf(cur[p].y) * c4.y;
            u.z = __expf(cur[p].z) * c4.z; u.w = __expf(cur[p].w) * c4.w;
            float s = group16_sum(u.x + u.y + u.z + u.w);
            float rold = rcur[p];
            float rnew = rold / (rold * s + EPS);
            float4 val;
            val.x = u.x * rnew; val.y = u.y * rnew;
            val.z = u.z * rnew; val.w = u.w * rnew;

            // top-1: per-lane best of 4 (lower col wins ties), group argmax
            float v = val.x; int i = base_col;
            if (val.y > v) { v = val.y; i = base_col + 1; }
            if (val.z > v) { v = val.z; i = base_col + 2; }
            if (val.w > v) { v = val.w; i = base_col + 3; }
            group16_argmax(v, i);
            float v1 = v; int i1 = i;

            float4 mv;
            mv.x = (i1 == base_col)     ? -INFINITY : val.x;
            mv.y = (i1 == base_col + 1) ? -INFINITY : val.y;
            mv.z = (i1 == base_col + 2) ? -INFINITY : val.z;
            mv.w = (i1 == base_col + 3) ? -INFINITY : val.w;
            v = mv.x; i = base_col;
            if (mv.y > v) { v = mv.y; i = base_col + 1; }
            if (mv.z > v) { v = mv.z; i = base_col + 2; }
            if (mv.w > v) { v = mv.w; i = base_col + 3; }
            group16_argmax(v, i);
            float v2 = v; int i2 = i;

            if (h == 0) {
                int row = (qbase + b * PF + p) * 4 + g;
                float wsum = v1 + v2 + EPS;
                oidx[row] = make_float2((float)i1, (float)i2);
                ow[row] = make_float2(v1 / wsum, v2 / wsum);
            }
        }
    }
}

extern "C" void kernel_launch(void* const* d_in, const int* in_sizes, int n_in,
                              void* d_out, int out_size, void* d_ws, size_t ws_size,
                              hipStream_t stream) {
    const float* logits = (const float*)d_in[0];
    const int S = in_sizes[0] / NE;            // 524288
    const int nquads = S / 4;                  // 131072 (divisible by NWAVES)
    const float col_target = (float)S / (float)NE;

    float* r = (float*)d_ws;                   // S floats
    float* c = r + S;                          // 64 floats
    float* Pblk = c + NE;                      // NBLOCKS*64 floats

    float* out = (float*)d_out;
    float2* oidx = (float2*)out;               // 2*S floats (indices)
    float2* ow = (float2*)(out + (size_t)2 * S);  // 2*S floats (weights)

    const float4* l4 = (const float4*)logits;

    sink_pass<true><<<NBLOCKS, THREADS, 0, stream>>>(l4, r, c, Pblk, nquads);
    sink_reduce<true><<<1, 1024, 0, stream>>>(Pblk, c, col_target);
    for (int it = 1; it < ITERS; ++it) {
        sink_pass<false><<<NBLOCKS, THREADS, 0, stream>>>(l4, r, c, Pblk, nquads);
        sink_reduce<false><<<1, 1024, 0, stream>>>(Pblk, c, col_target);
    }
    sink_final<<<NBLOCKS, THREADS, 0, stream>>>(l4, r, c, oidx, ow, nquads);
}

// Round 6
// 554.621 us; speedup vs baseline: 2.4639x; 1.1071x over previous
//
#include <hip/hip_runtime.h>
#include <math.h>

#define EPS 1e-6f
#define NE 64
#define TPB 1024
#define WPB 16             // waves per block
#define NBLK 256
#define NWAVES (NBLK * WPB)   // 4096
#define ITERS 10
#define PF 4               // prefetch depth (quads per batch)

// ---- DPP helpers: 16-lane-group reductions, pure VALU (no ds ops) ----
template <int ctrl>
__device__ __forceinline__ float dppf(float x) {
    return __int_as_float(__builtin_amdgcn_update_dpp(
        0, __float_as_int(x), ctrl, 0xf, 0xf, true));
}
template <int ctrl>
__device__ __forceinline__ int dppi(int x) {
    return __builtin_amdgcn_update_dpp(0, x, ctrl, 0xf, 0xf, true);
}

__device__ __forceinline__ float group16_sum(float v) {
    v += dppf<0xB1>(v);   // quad_perm xor 1
    v += dppf<0x4E>(v);   // quad_perm xor 2
    v += dppf<0x141>(v);  // row_half_mirror (xor 4)
    v += dppf<0x140>(v);  // row_mirror (xor 8)
    return v;
}

#define ARGMAX_STEP(CTRL)                                      \
    {                                                          \
        float ov = dppf<CTRL>(v);                              \
        int oi = dppi<CTRL>(i);                                \
        if (ov > v || (ov == v && oi < i)) { v = ov; i = oi; } \
    }

__device__ __forceinline__ void group16_argmax(float& v, int& i) {
    ARGMAX_STEP(0xB1)
    ARGMAX_STEP(0x4E)
    ARGMAX_STEP(0x141)
    ARGMAX_STEP(0x140)
}

// ws layout: r[S] | c[64] | Pblk[NBLK*64] | counters[ITERS]
// One Sinkhorn iteration; the LAST block to finish (atomic counter) also
// performs the fixed-order column reduce and updates c. Arrival order never
// enters the arithmetic -> bitwise deterministic across replays.
template <bool FIRST>
__global__ __launch_bounds__(TPB) void sink_pass(
    const float4* __restrict__ logits4, float* __restrict__ r,
    float* __restrict__ c, float* __restrict__ Pblk,
    unsigned* __restrict__ counters, int nquads, float col_target, int it) {
    const int tid = threadIdx.x;
    const int lane = tid & 63;
    const int wib = tid >> 6;
    const int g = lane >> 4;   // row within quad
    const int h = lane & 15;   // float4 slot within row
    const int qpw = nquads / NWAVES;                 // 32
    const int qbase = (blockIdx.x * WPB + wib) * qpw;

    float4 c4;
    if (FIRST) c4 = make_float4(1.f, 1.f, 1.f, 1.f);
    else       c4 = ((const float4*)c)[h];

    const float4* lp = logits4 + (size_t)qbase * 64 + lane;

    float4 buf[PF];
    float rbuf[PF];
#pragma unroll
    for (int p = 0; p < PF; ++p) buf[p] = lp[(size_t)p * 64];
    if (!FIRST) {
#pragma unroll
        for (int p = 0; p < PF; ++p) rbuf[p] = r[(qbase + p) * 4 + g];
    }

    float4 pacc = {0.f, 0.f, 0.f, 0.f};
    const int nb = qpw / PF;
    for (int b = 0; b < nb; ++b) {
        float4 cur[PF];
        float rcur[PF];
#pragma unroll
        for (int p = 0; p < PF; ++p) {
            cur[p] = buf[p];
            if (!FIRST) rcur[p] = rbuf[p];
        }
        if (b + 1 < nb) {
            const float4* np = lp + (size_t)(b + 1) * PF * 64;
#pragma unroll
            for (int p = 0; p < PF; ++p) buf[p] = np[(size_t)p * 64];
            if (!FIRST) {
#pragma unroll
                for (int p = 0; p < PF; ++p)
                    rbuf[p] = r[(qbase + (b + 1) * PF + p) * 4 + g];
            }
        }
#pragma unroll
        for (int p = 0; p < PF; ++p) {
            float4 q;
            q.x = __expf(cur[p].x); q.y = __expf(cur[p].y);
            q.z = __expf(cur[p].z); q.w = __expf(cur[p].w);
            float s = q.x * c4.x + q.y * c4.y + q.z * c4.z + q.w * c4.w;
            s = group16_sum(s);
            float rold = FIRST ? 1.0f : rcur[p];
            float rnew = rold / (rold * s + EPS);
            int row = (qbase + b * PF + p) * 4 + g;
            if (h == 0) r[row] = rnew;
            pacc.x += q.x * rnew; pacc.y += q.y * rnew;
            pacc.z += q.z * rnew; pacc.w += q.w * rnew;
        }
    }

    // ---- block-level column reduction (fixed order), store partials ----
    __shared__ float4 plds[WPB][64];        // 16 KB; reused as reduce buffer
    __shared__ int lastflag;
    plds[wib][lane] = pacc;
    __syncthreads();
    if (tid < NE) {
        int j = tid, hh = j >> 2, kk = j & 3;
        float t = 0.f;
#pragma unroll
        for (int w = 0; w < WPB; ++w)
#pragma unroll
            for (int gg = 0; gg < 4; ++gg)
                t += ((const float*)&plds[w][gg * 16 + hh])[kk];
        Pblk[blockIdx.x * NE + j] = t;
        __threadfence();                    // release partials (device scope)
    }
    __syncthreads();
    if (tid == 0) {
        unsigned old = atomicAdd(&counters[it], 1u);
        lastflag = (old == (unsigned)(NBLK - 1));
    }
    __syncthreads();

    if (lastflag) {
        __threadfence();                    // acquire all blocks' partials
        float* s_red = (float*)plds;        // [16][NE], plds content dead now
        const int j = tid & 63;
        const int chunk = tid >> 6;         // 16 chunks of NBLK/16=16 blocks
        float t = 0.f;
        int b0 = chunk * (NBLK / 16);
        for (int b = b0; b < b0 + NBLK / 16; ++b) t += Pblk[b * NE + j];
        __syncthreads();
        s_red[chunk * NE + j] = t;
        __syncthreads();
        if (tid < NE) {
            float P = 0.f;
#pragma unroll
            for (int k = 0; k < 16; ++k) P += s_red[k * NE + tid];
            float cj = FIRST ? 1.0f : c[tid];
            c[tid] = cj * col_target / (cj * P + EPS);
            __threadfence();                // release c for the next pass
        }
    }
}

// Final: row-normalize + top-2 (DPP argmax, lowest-index ties) + renorm.
// Reads ORIGINAL fp32 logits -> numerics identical to the validated R5 path.
__global__ __launch_bounds__(TPB) void sink_final(
    const float4* __restrict__ logits4, const float* __restrict__ r,
    const float* __restrict__ c, float2* __restrict__ oidx,
    float2* __restrict__ ow, int nquads) {
    const int tid = threadIdx.x;
    const int lane = tid & 63;
    const int wib = tid >> 6;
    const int g = lane >> 4;
    const int h = lane & 15;
    const int base_col = h * 4;
    const int qpw = nquads / NWAVES;
    const int qbase = (blockIdx.x * WPB + wib) * qpw;

    const float4 c4 = ((const float4*)c)[h];
    const float4* lp = logits4 + (size_t)qbase * 64 + lane;

    float4 buf[PF];
    float rbuf[PF];
#pragma unroll
    for (int p = 0; p < PF; ++p) buf[p] = lp[(size_t)p * 64];
#pragma unroll
    for (int p = 0; p < PF; ++p) rbuf[p] = r[(qbase + p) * 4 + g];

    const int nb = qpw / PF;
    for (int b = 0; b < nb; ++b) {
        float4 cur[PF];
        float rcur[PF];
#pragma unroll
        for (int p = 0; p < PF; ++p) { cur[p] = buf[p]; rcur[p] = rbuf[p]; }
        if (b + 1 < nb) {
            const float4* np = lp + (size_t)(b + 1) * PF * 64;
#pragma unroll
            for (int p = 0; p < PF; ++p) buf[p] = np[(size_t)p * 64];
#pragma unroll
            for (int p = 0; p < PF; ++p)
                rbuf[p] = r[(qbase + (b + 1) * PF + p) * 4 + g];
        }
#pragma unroll
        for (int p = 0; p < PF; ++p) {
            float4 u;
            u.x = __expf(cur[p].x) * c4.x; u.y = __expf(cur[p].y) * c4.y;
            u.z = __expf(cur[p].z) * c4.z; u.w = __expf(cur[p].w) * c4.w;
            float s = group16_sum(u.x + u.y + u.z + u.w);
            float rold = rcur[p];
            float rnew = rold / (rold * s + EPS);
            float4 val;
            val.x = u.x * rnew; val.y = u.y * rnew;
            val.z = u.z * rnew; val.w = u.w * rnew;

            // top-1: per-lane best of 4 (lower col wins ties), group argmax
            float v = val.x; int i = base_col;
            if (val.y > v) { v = val.y; i = base_col + 1; }
            if (val.z > v) { v = val.z; i = base_col + 2; }
            if (val.w > v) { v = val.w; i = base_col + 3; }
            group16_argmax(v, i);
            float v1 = v; int i1 = i;

            float4 mv;
            mv.x = (i1 == base_col)     ? -INFINITY : val.x;
            mv.y = (i1 == base_col + 1) ? -INFINITY : val.y;
            mv.z = (i1 == base_col + 2) ? -INFINITY : val.z;
            mv.w = (i1 == base_col + 3) ? -INFINITY : val.w;
            v = mv.x; i = base_col;
            if (mv.y > v) { v = mv.y; i = base_col + 1; }
            if (mv.z > v) { v = mv.z; i = base_col + 2; }
            if (mv.w > v) { v = mv.w; i = base_col + 3; }
            group16_argmax(v, i);
            float v2 = v; int i2 = i;

            if (h == 0) {
                int row = (qbase + b * PF + p) * 4 + g;
                float wsum = v1 + v2 + EPS;
                oidx[row] = make_float2((float)i1, (float)i2);
                ow[row] = make_float2(v1 / wsum, v2 / wsum);
            }
        }
    }
}

extern "C" void kernel_launch(void* const* d_in, const int* in_sizes, int n_in,
                              void* d_out, int out_size, void* d_ws, size_t ws_size,
                              hipStream_t stream) {
    const float* logits = (const float*)d_in[0];
    const int S = in_sizes[0] / NE;            // 524288
    const int nquads = S / 4;                  // 131072 (divisible by NWAVES)
    const float col_target = (float)S / (float)NE;

    float* r = (float*)d_ws;                   // S floats
    float* c = r + S;                          // 64 floats
    float* Pblk = c + NE;                      // NBLK*64 floats
    unsigned* counters = (unsigned*)(Pblk + NBLK * NE);  // ITERS slots

    float* out = (float*)d_out;
    float2* oidx = (float2*)out;               // 2*S floats (indices)
    float2* ow = (float2*)(out + (size_t)2 * S);  // 2*S floats (weights)

    const float4* l4 = (const float4*)logits;

    hipMemsetAsync(counters, 0, ITERS * sizeof(unsigned), stream);
    sink_pass<true><<<NBLK, TPB, 0, stream>>>(l4, r, c, Pblk, counters,
                                              nquads, col_target, 0);
    for (int it = 1; it < ITERS; ++it)
        sink_pass<false><<<NBLK, TPB, 0, stream>>>(l4, r, c, Pblk, counters,
                                                   nquads, col_target, it);
    sink_final<<<NBLK, TPB, 0, stream>>>(l4, r, c, oidx, ow, nquads);
}